// Round 7
// baseline (161.062 us; speedup 1.0000x reference)
//
#include <hip/hip_runtime.h>

#define T_LEN     2000000
#define NT        5
#define START_TAG 3
#define STOP_TAG  4
#define CH        8              // time steps per thread
#define BTHR      256
#define NBLK      1024           // 1024*256*8 = 2,097,152 >= 2e6
#define SPB       (BTHR * CH)    // 2048 steps per block
#define GOFF      (NBLK * 13)    // float index of gold partials in ws
#define ID_OFF    (-1.0e30f)     // sentinel: identity element

// Reduced scaled transfer matrix: rows {0,1,2} x cols {0,1,2,START}, slot 12 =
// log offset. Rows START/STOP and col STOP are semiring-zero (exp(NEG)=0) and
// contribute nothing to alpha, so they are dropped. off < -1e29 = identity.
__device__ __forceinline__ void compose13(const float* L, const float* R, float* C) {
    float t[12];
#pragma unroll
    for (int j = 0; j < 3; ++j)
#pragma unroll
        for (int s = 0; s < 4; ++s)
            t[j * 4 + s] = fmaf(L[j * 4 + 0], R[0 * 4 + s],
                           fmaf(L[j * 4 + 1], R[1 * 4 + s],
                                L[j * 4 + 2] * R[2 * 4 + s]));
    float m = t[0];
#pragma unroll
    for (int k = 1; k < 12; ++k) m = fmaxf(m, t[k]);
    const float r    = 1.0f / m;
    const float toff = L[12] + R[12] + __logf(m);
    const bool  Lid  = L[12] < -1e29f;
    const bool  Rid  = R[12] < -1e29f;
#pragma unroll
    for (int k = 0; k < 12; ++k)
        C[k] = Rid ? L[k] : (Lid ? R[k] : t[k] * r);
    C[12] = Rid ? L[12] : (Lid ? R[12] : toff);
}

// 64-lane order-aware butterfly: lane i holds time-segment i (13 floats + gold).
// After 6 levels every lane holds the full in-order product. (verified R4/R5)
__device__ __forceinline__ void wave_tree(float* acc, float& g, int lane) {
#pragma unroll
    for (int d = 1; d < 64; d <<= 1) {
        float P[13], C[13];
#pragma unroll
        for (int k = 0; k < 13; ++k) P[k] = __shfl_xor(acc[k], d, 64);
        const float gp = __shfl_xor(g, d, 64);
        if (lane & d) compose13(acc, P, C);   // mine is the later segment
        else          compose13(P, acc, C);   // partner is later
#pragma unroll
        for (int k = 0; k < 13; ++k) acc[k] = C[k];
        g += gp;
    }
}

__global__ __launch_bounds__(BTHR, 4) void crf_phase1(
    const float* __restrict__ feats, const int* __restrict__ tags,
    const float* __restrict__ trans, float* __restrict__ ws)
{
    // LDS: reduce buffers only (14336 B) + trans (100 B)
    __shared__ float sM[BTHR * 13];
    __shared__ float sG[BTHR];
    __shared__ float sTr[NT * NT];

    const int tid = threadIdx.x;
    if (tid < NT * NT) sTr[tid] = trans[tid];
    __syncthreads();                                 // before any global loads -> no vmcnt drain

    const long start  = (long)blockIdx.x * SPB + (long)tid * CH;
    const bool active = (start < T_LEN);             // active chunks always full (2e6 % 8 == 0)

    float A[12];
    float off  = ID_OFF;
    float gold = 0.0f;

    if (active) {
        // ---- direct per-thread loads: 160 B feats (10x float4) + 32 B tags (2x int4) ----
        __align__(16) float fr[CH * NT];             // stays in VGPRs (all indices constant)
        const float* gF = feats + start * NT;        // byte offset start*20 -> 16B-aligned (CH*NT*4=160)
#pragma unroll
        for (int k = 0; k < (CH * NT) / 4; ++k)
            *(float4*)(fr + 4 * k) = *(const float4*)(gF + 4 * k);

        int tg[CH];
        {
            const int4 a = *(const int4*)(tags + start);
            const int4 b = *(const int4*)(tags + start + 4);
            tg[0] = a.x; tg[1] = a.y; tg[2] = a.z; tg[3] = a.w;
            tg[4] = b.x; tg[5] = b.y; tg[6] = b.z; tg[7] = b.w;
        }
        // boundary tag: one extra dword load (2 lanes/line), no barrier needed
        int prev = START_TAG;
        if (start > 0) prev = tags[start - 1];

        // E[j][s] = exp(trans[j][s]), j in {0,1,2}, s in {0,1,2,START}
        float E[12];
#pragma unroll
        for (int j = 0; j < 3; ++j)
#pragma unroll
            for (int s = 0; s < 4; ++s)
                E[j * 4 + s] = __expf(sTr[j * NT + s]);

        // step 0: A = diag(e) * E   (A_prev = I on live rows/cols)
        {
            const float f0 = fr[0], f1 = fr[1], f2 = fr[2];
            const float e0 = __expf(f0), e1 = __expf(f1), e2 = __expf(f2);
#pragma unroll
            for (int s = 0; s < 4; ++s) {
                A[0 * 4 + s] = e0 * E[0 * 4 + s];
                A[1 * 4 + s] = e1 * E[1 * 4 + s];
                A[2 * 4 + s] = e2 * E[2 * 4 + s];
            }
            const int t0 = tg[0];
            gold = sTr[t0 * NT + prev] + (t0 == 0 ? f0 : (t0 == 1 ? f1 : f2));
            prev = t0;
        }
        // steps 1..7
#pragma unroll
        for (int t = 1; t < CH; ++t) {
            const float f0 = fr[t * NT + 0], f1 = fr[t * NT + 1], f2 = fr[t * NT + 2];
            const float e0 = __expf(f0), e1 = __expf(f1), e2 = __expf(f2);
            float N[12];
#pragma unroll
            for (int s = 0; s < 4; ++s) {
                const float a0 = A[0 * 4 + s], a1 = A[1 * 4 + s], a2 = A[2 * 4 + s];
                N[0 * 4 + s] = e0 * fmaf(E[0], a0, fmaf(E[1], a1, E[2] * a2));
                N[1 * 4 + s] = e1 * fmaf(E[4], a0, fmaf(E[5], a1, E[6] * a2));
                N[2 * 4 + s] = e2 * fmaf(E[8], a0, fmaf(E[9], a1, E[10] * a2));
            }
#pragma unroll
            for (int k = 0; k < 12; ++k) A[k] = N[k];

            const int t1 = tg[t];
            gold += sTr[t1 * NT + prev] + (t1 == 0 ? f0 : (t1 == 1 ? f1 : f2));
            prev = t1;
        }
        // normalize once per chunk (max growth ~e^75 from 1.0 — safe fp32; verified R3)
        float m = A[0];
#pragma unroll
        for (int k = 1; k < 12; ++k) m = fmaxf(m, A[k]);
        const float r = 1.0f / m;
#pragma unroll
        for (int k = 0; k < 12; ++k) A[k] *= r;
        off = __logf(m);

        if (start + CH == T_LEN) gold += sTr[STOP_TAG * NT + prev];
    } else {
#pragma unroll
        for (int k = 0; k < 12; ++k) A[k] = 0.0f;
    }

    // ---- block reduce: LDS store once, 64 lanes compose 4, then shuffle tree ----
#pragma unroll
    for (int k = 0; k < 12; ++k) sM[tid * 13 + k] = A[k];
    sM[tid * 13 + 12] = off;
    sG[tid]           = gold;
    __syncthreads();

    if (tid < 64) {
        float acc[13];
#pragma unroll
        for (int k = 0; k < 13; ++k) acc[k] = sM[(4 * tid) * 13 + k];
        float g = sG[4 * tid];
#pragma unroll
        for (int q = 1; q < 4; ++q) {
            float nxt[13], C[13];
#pragma unroll
            for (int k = 0; k < 13; ++k) nxt[k] = sM[(4 * tid + q) * 13 + k];
            compose13(nxt, acc, C);
#pragma unroll
            for (int k = 0; k < 13; ++k) acc[k] = C[k];
            g += sG[4 * tid + q];
        }
        wave_tree(acc, g, tid);

        // all 64 lanes hold the block result; lanes 0..13 store it
        float v = acc[0];
#pragma unroll
        for (int k = 1; k < 13; ++k) v = (tid == k) ? acc[k] : v;
        if (tid < 13)  ws[blockIdx.x * 13 + tid] = v;
        if (tid == 13) ws[GOFF + blockIdx.x] = g;
    }
}

__global__ __launch_bounds__(256) void crf_phase2(
    const float* __restrict__ trans, const float* __restrict__ ws,
    float* __restrict__ out)
{
    __shared__ float sM[256 * 13];
    __shared__ float sG[256];

    const int tid = threadIdx.x;

    // each thread composes 4 consecutive block matrices in time order
    {
        float acc[13], nxt[13], C[13];
#pragma unroll
        for (int k = 0; k < 13; ++k) acc[k] = ws[(4 * tid) * 13 + k];
        float g = ws[GOFF + 4 * tid];
#pragma unroll
        for (int q = 1; q < 4; ++q) {
#pragma unroll
            for (int k = 0; k < 13; ++k) nxt[k] = ws[(4 * tid + q) * 13 + k];
            compose13(nxt, acc, C);
#pragma unroll
            for (int k = 0; k < 13; ++k) acc[k] = C[k];
            g += ws[GOFF + 4 * tid + q];
        }
#pragma unroll
        for (int k = 0; k < 13; ++k) sM[tid * 13 + k] = acc[k];
        sG[tid] = g;
    }
    __syncthreads();

    if (tid < 64) {
        float acc[13];
#pragma unroll
        for (int k = 0; k < 13; ++k) acc[k] = sM[(4 * tid) * 13 + k];
        float g = sG[4 * tid];
#pragma unroll
        for (int q = 1; q < 4; ++q) {
            float nxt[13], C[13];
#pragma unroll
            for (int k = 0; k < 13; ++k) nxt[k] = sM[(4 * tid + q) * 13 + k];
            compose13(nxt, acc, C);
#pragma unroll
            for (int k = 0; k < 13; ++k) acc[k] = C[k];
            g += sG[4 * tid + q];
        }
        wave_tree(acc, g, tid);

        if (tid == 0) {
            // alpha = off + log( sum_{j<3} M[j][START] * exp(trans[STOP][j]) )
            float s = 0.0f;
#pragma unroll
            for (int j = 0; j < 3; ++j)
                s += acc[j * 4 + 3] * __expf(trans[STOP_TAG * NT + j]);
            const float alpha = acc[12] + __logf(s);
            out[0] = alpha - g;
        }
    }
}

extern "C" void kernel_launch(void* const* d_in, const int* in_sizes, int n_in,
                              void* d_out, int out_size, void* d_ws, size_t ws_size,
                              hipStream_t stream) {
    const float* feats = (const float*)d_in[0];
    const int*   tags  = (const int*)d_in[1];
    const float* trans = (const float*)d_in[2];
    float*       out   = (float*)d_out;
    float*       ws    = (float*)d_ws;

    // real pipeline (identical to the 96.9 µs baseline)
    crf_phase1<<<NBLK, BTHR, 0, stream>>>(feats, tags, trans, ws);
    crf_phase2<<<1, 256, 0, stream>>>(trans, ws, out);

    // ---- DIAGNOSTIC: 4 duplicate phase1 dispatches into scratch ws regions ----
    // Purpose: measure phase1's true marginal cost inside the timed window.
    // dur_us - 96.9 ≈ 4 x (warm_phase1 + node_overhead). Each dup needs
    // GOFF+NBLK = 14336 floats; offsets 4M..16M floats are far inside the
    // 64M-float (256 MiB) workspace and untouched by phase2.
    crf_phase1<<<NBLK, BTHR, 0, stream>>>(feats, tags, trans, ws + (1u << 22));
    crf_phase1<<<NBLK, BTHR, 0, stream>>>(feats, tags, trans, ws + (2u << 22));
    crf_phase1<<<NBLK, BTHR, 0, stream>>>(feats, tags, trans, ws + (3u << 22));
    crf_phase1<<<NBLK, BTHR, 0, stream>>>(feats, tags, trans, ws + (4u << 22));
}

// Round 8
// 96.302 us; speedup vs baseline: 1.6725x; 1.6725x over previous
//
#include <hip/hip_runtime.h>

#define T_LEN     2000000
#define NT        5
#define START_TAG 3
#define STOP_TAG  4
#define CH        8              // time steps per thread
#define BTHR      256
#define NBLK      1024           // 1024*256*8 = 2,097,152 >= 2e6
#define SPB       (BTHR * CH)    // 2048 steps per block
#define GOFF      (NBLK * 10)    // float index of gold partials in ws
#define ID_OFF    (-1.0e30f)     // sentinel: identity element

// Reduced scaled transfer: 3x3 over live states {0,1,2}; slot 9 = log offset.
// START/STOP rows/cols are semiring-zero. The global init vector e_START is
// embedded by the start==0 thread as column 0 of its chunk (cols 1,2 = 0);
// left-multiplies preserve this, so M_total[:,0] = old M_total[:,START].
// off < -1e29 = identity sentinel.
__device__ __forceinline__ void compose10(const float* L, const float* R, float* C) {
    float t[9];
#pragma unroll
    for (int j = 0; j < 3; ++j)
#pragma unroll
        for (int s = 0; s < 3; ++s)
            t[j * 3 + s] = fmaf(L[j * 3 + 0], R[0 * 3 + s],
                           fmaf(L[j * 3 + 1], R[1 * 3 + s],
                                L[j * 3 + 2] * R[2 * 3 + s]));
    float m = t[0];
#pragma unroll
    for (int k = 1; k < 9; ++k) m = fmaxf(m, t[k]);
    const float r    = 1.0f / m;
    const float toff = L[9] + R[9] + __logf(m);
    const bool  Lid  = L[9] < -1e29f;
    const bool  Rid  = R[9] < -1e29f;
#pragma unroll
    for (int k = 0; k < 9; ++k)
        C[k] = Rid ? L[k] : (Lid ? R[k] : t[k] * r);
    C[9] = Rid ? L[9] : (Lid ? R[9] : toff);
}

// 64-lane order-aware butterfly: lane i holds time-segment i (10 floats + gold).
// After 6 levels every lane holds the full in-order product. Earliest segment
// always enters compose as the R operand (order-aware), so the boundary
// column-0 embedding is preserved.
__device__ __forceinline__ void wave_tree(float* acc, float& g, int lane) {
#pragma unroll
    for (int d = 1; d < 64; d <<= 1) {
        float P[10], C[10];
#pragma unroll
        for (int k = 0; k < 10; ++k) P[k] = __shfl_xor(acc[k], d, 64);
        const float gp = __shfl_xor(g, d, 64);
        if (lane & d) compose10(acc, P, C);   // mine is the later segment
        else          compose10(P, acc, C);   // partner is later
#pragma unroll
        for (int k = 0; k < 10; ++k) acc[k] = C[k];
        g += gp;
    }
}

__global__ __launch_bounds__(BTHR, 4) void crf_phase1(
    const float* __restrict__ feats, const int* __restrict__ tags,
    const float* __restrict__ trans, float* __restrict__ ws)
{
    // LDS: reduce buffers (10240 B) + gold (1024 B) + trans (100 B)
    __shared__ float sM[BTHR * 10];
    __shared__ float sG[BTHR];
    __shared__ float sTr[NT * NT];

    const int tid = threadIdx.x;
    if (tid < NT * NT) sTr[tid] = trans[tid];
    __syncthreads();                                 // before any global loads -> no vmcnt drain

    const long start  = (long)blockIdx.x * SPB + (long)tid * CH;
    const bool active = (start < T_LEN);             // active chunks always full (2e6 % 8 == 0)

    float A[9];
    float off  = ID_OFF;
    float gold = 0.0f;

    if (active) {
        // ---- direct per-thread loads: 160 B feats (10x float4) + 32 B tags (2x int4) ----
        __align__(16) float fr[CH * NT];             // stays in VGPRs (all indices constant)
        const float* gF = feats + start * NT;        // byte offset start*20 -> 16B-aligned (CH*NT*4=160)
#pragma unroll
        for (int k = 0; k < (CH * NT) / 4; ++k)
            *(float4*)(fr + 4 * k) = *(const float4*)(gF + 4 * k);

        int tg[CH];
        {
            const int4 a = *(const int4*)(tags + start);
            const int4 b = *(const int4*)(tags + start + 4);
            tg[0] = a.x; tg[1] = a.y; tg[2] = a.z; tg[3] = a.w;
            tg[4] = b.x; tg[5] = b.y; tg[6] = b.z; tg[7] = b.w;
        }
        // boundary tag: one extra dword load (2 lanes/line), no barrier needed
        int prev = START_TAG;
        if (start > 0) prev = tags[start - 1];

        // E[j][k] = exp(trans[j][k]), j,k in {0,1,2} (3x3 live block)
        float E[9];
#pragma unroll
        for (int j = 0; j < 3; ++j)
#pragma unroll
            for (int s = 0; s < 3; ++s)
                E[j * 3 + s] = __expf(sTr[j * NT + s]);

        // step 0
        {
            const float f0 = fr[0], f1 = fr[1], f2 = fr[2];
            const float e0 = __expf(f0), e1 = __expf(f1), e2 = __expf(f2);
            if (start == 0) {
                // global boundary: init vector e_START -> column 0; cols 1,2 = 0
                A[0] = e0 * __expf(sTr[0 * NT + START_TAG]);
                A[3] = e1 * __expf(sTr[1 * NT + START_TAG]);
                A[6] = e2 * __expf(sTr[2 * NT + START_TAG]);
                A[1] = A[2] = A[4] = A[5] = A[7] = A[8] = 0.0f;
            } else {
                // A_prev = I on live states: A = diag(e) * E
#pragma unroll
                for (int s = 0; s < 3; ++s) {
                    A[0 * 3 + s] = e0 * E[0 * 3 + s];
                    A[1 * 3 + s] = e1 * E[1 * 3 + s];
                    A[2 * 3 + s] = e2 * E[2 * 3 + s];
                }
            }
            const int t0 = tg[0];
            gold = sTr[t0 * NT + prev] + (t0 == 0 ? f0 : (t0 == 1 ? f1 : f2));
            prev = t0;
        }
        // steps 1..7
#pragma unroll
        for (int t = 1; t < CH; ++t) {
            const float f0 = fr[t * NT + 0], f1 = fr[t * NT + 1], f2 = fr[t * NT + 2];
            const float e0 = __expf(f0), e1 = __expf(f1), e2 = __expf(f2);
            float N[9];
#pragma unroll
            for (int s = 0; s < 3; ++s) {
                const float a0 = A[0 * 3 + s], a1 = A[1 * 3 + s], a2 = A[2 * 3 + s];
                N[0 * 3 + s] = e0 * fmaf(E[0], a0, fmaf(E[1], a1, E[2] * a2));
                N[1 * 3 + s] = e1 * fmaf(E[3], a0, fmaf(E[4], a1, E[5] * a2));
                N[2 * 3 + s] = e2 * fmaf(E[6], a0, fmaf(E[7], a1, E[8] * a2));
            }
#pragma unroll
            for (int k = 0; k < 9; ++k) A[k] = N[k];

            const int t1 = tg[t];
            gold += sTr[t1 * NT + prev] + (t1 == 0 ? f0 : (t1 == 1 ? f1 : f2));
            prev = t1;
        }
        // normalize once per chunk (entries positive; boundary chunk: col 0 > 0,
        // cols 1,2 stay exactly 0 — max comes from col 0; safe fp32)
        float m = A[0];
#pragma unroll
        for (int k = 1; k < 9; ++k) m = fmaxf(m, A[k]);
        const float r = 1.0f / m;
#pragma unroll
        for (int k = 0; k < 9; ++k) A[k] *= r;
        off = __logf(m);

        if (start + CH == T_LEN) gold += sTr[STOP_TAG * NT + prev];
    } else {
#pragma unroll
        for (int k = 0; k < 9; ++k) A[k] = 0.0f;
    }

    // ---- block reduce: LDS store once, 64 lanes compose 4, then shuffle tree ----
#pragma unroll
    for (int k = 0; k < 9; ++k) sM[tid * 10 + k] = A[k];
    sM[tid * 10 + 9] = off;
    sG[tid]          = gold;
    __syncthreads();

    if (tid < 64) {
        float acc[10];
#pragma unroll
        for (int k = 0; k < 10; ++k) acc[k] = sM[(4 * tid) * 10 + k];
        float g = sG[4 * tid];
#pragma unroll
        for (int q = 1; q < 4; ++q) {
            float nxt[10], C[10];
#pragma unroll
            for (int k = 0; k < 10; ++k) nxt[k] = sM[(4 * tid + q) * 10 + k];
            compose10(nxt, acc, C);                  // nxt later, acc earlier
#pragma unroll
            for (int k = 0; k < 10; ++k) acc[k] = C[k];
            g += sG[4 * tid + q];
        }
        wave_tree(acc, g, tid);

        // all 64 lanes hold the block result; lanes 0..10 store it
        float v = acc[0];
#pragma unroll
        for (int k = 1; k < 10; ++k) v = (tid == k) ? acc[k] : v;
        if (tid < 10)  ws[blockIdx.x * 10 + tid] = v;
        if (tid == 10) ws[GOFF + blockIdx.x] = g;
    }
}

__global__ __launch_bounds__(256) void crf_phase2(
    const float* __restrict__ trans, const float* __restrict__ ws,
    float* __restrict__ out)
{
    __shared__ float sM[256 * 10];
    __shared__ float sG[256];

    const int tid = threadIdx.x;

    // each thread composes 4 consecutive block matrices in time order
    {
        float acc[10], nxt[10], C[10];
#pragma unroll
        for (int k = 0; k < 10; ++k) acc[k] = ws[(4 * tid) * 10 + k];
        float g = ws[GOFF + 4 * tid];
#pragma unroll
        for (int q = 1; q < 4; ++q) {
#pragma unroll
            for (int k = 0; k < 10; ++k) nxt[k] = ws[(4 * tid + q) * 10 + k];
            compose10(nxt, acc, C);
#pragma unroll
            for (int k = 0; k < 10; ++k) acc[k] = C[k];
            g += ws[GOFF + 4 * tid + q];
        }
#pragma unroll
        for (int k = 0; k < 10; ++k) sM[tid * 10 + k] = acc[k];
        sG[tid] = g;
    }
    __syncthreads();

    if (tid < 64) {
        float acc[10];
#pragma unroll
        for (int k = 0; k < 10; ++k) acc[k] = sM[(4 * tid) * 10 + k];
        float g = sG[4 * tid];
#pragma unroll
        for (int q = 1; q < 4; ++q) {
            float nxt[10], C[10];
#pragma unroll
            for (int k = 0; k < 10; ++k) nxt[k] = sM[(4 * tid + q) * 10 + k];
            compose10(nxt, acc, C);
#pragma unroll
            for (int k = 0; k < 10; ++k) acc[k] = C[k];
            g += sG[4 * tid + q];
        }
        wave_tree(acc, g, tid);

        if (tid == 0) {
            // col 0 of the total product = image of the init vector e_START.
            // alpha = off + log( sum_{j<3} v[j] * exp(trans[STOP][j]) )
            float s = 0.0f;
#pragma unroll
            for (int j = 0; j < 3; ++j)
                s += acc[j * 3 + 0] * __expf(trans[STOP_TAG * NT + j]);
            const float alpha = acc[9] + __logf(s);
            out[0] = alpha - g;
        }
    }
}

extern "C" void kernel_launch(void* const* d_in, const int* in_sizes, int n_in,
                              void* d_out, int out_size, void* d_ws, size_t ws_size,
                              hipStream_t stream) {
    const float* feats = (const float*)d_in[0];
    const int*   tags  = (const int*)d_in[1];
    const float* trans = (const float*)d_in[2];
    float*       out   = (float*)d_out;
    float*       ws    = (float*)d_ws;

    crf_phase1<<<NBLK, BTHR, 0, stream>>>(feats, tags, trans, ws);
    crf_phase2<<<1, 256, 0, stream>>>(trans, ws, out);
}